// Round 8
// baseline (474.049 us; speedup 1.0000x reference)
//
#include <hip/hip_runtime.h>
#include <hip/hip_bf16.h>

#define NN 8192
#define KF 512
#define FF 64
#define GAT_ALPHA 0.2f
#define MSHIFT 20.0f          // safe upper bound on max_j e2[j] (pre-scale)
#define LOG2E 1.44269504f

#define JSPLIT 8              // grid = 128 row-groups x 8 = 1024 blocks = 4/CU
#define JW (NN / JSPLIT)      // 1024 j per wave
#define KSTEPS (JW / 32)      // 32 k-steps of 32

#define EXP2F(x) __builtin_amdgcn_exp2f(x)

typedef __attribute__((ext_vector_type(8))) __bf16 bf16x8;
typedef __attribute__((ext_vector_type(4))) float f32x4;

// ---------------------------------------------------------------------------
// adj_compress: 268 MB int32 adjacency -> 8 MB bitmask, transposed to the
// MFMA A-fragment lane order: byte addr = row*1024 + split*128 + quad*32 + st,
// bit jj of that byte = adj[row][split*1024 + st*32 + quad*8 + jj] > 0.
// Pure streaming read (each thread 128 B), coalesced dword writes.
// ---------------------------------------------------------------------------
__global__ __launch_bounds__(256) void adj_compress(
    const int* __restrict__ adj, unsigned* __restrict__ mask)
{
    const int b   = blockIdx.x * 256 + threadIdx.x;  // dword index, 2M total
    const int st4 =  b       & 7;                    // st group (4 steps/dword)
    const int q   = (b >> 3) & 3;
    const int s   = (b >> 5) & 7;
    const int row =  b >> 8;

    const int* ap = adj + (size_t)row * NN + s * JW + q * 8;
    unsigned w = 0;
    #pragma unroll
    for (int k = 0; k < 4; ++k) {
        const int st = st4 * 4 + k;
        int4 a0 = *(const int4*)(ap + st * 32);
        int4 a1 = *(const int4*)(ap + st * 32 + 4);
        unsigned by =  (unsigned)(a0.x > 0)
                    | ((unsigned)(a0.y > 0) << 1)
                    | ((unsigned)(a0.z > 0) << 2)
                    | ((unsigned)(a0.w > 0) << 3)
                    | ((unsigned)(a1.x > 0) << 4)
                    | ((unsigned)(a1.y > 0) << 5)
                    | ((unsigned)(a1.z > 0) << 6)
                    | ((unsigned)(a1.w > 0) << 7);
        w |= by << (8 * k);
    }
    mask[b] = w;
}

// ---------------------------------------------------------------------------
// Kernel A: h = x@W (fp32), e1/e2 = (h@a1, h@a2) * log2(e),
//           ht = h^T bf16 [64][8192]. 256 blocks x 256 thr, 32 rows/block.
// ---------------------------------------------------------------------------
__global__ __launch_bounds__(256) void gat_linear(
    const float* __restrict__ x, const float* __restrict__ W,
    const float* __restrict__ av, __hip_bfloat16* __restrict__ ht,
    float* __restrict__ e1, float* __restrict__ e2)
{
    __shared__ float xs[32][33];
    __shared__ float Ws[32][64];
    __shared__ float ep[2][32][17];

    const int t  = threadIdx.x;
    const int fq = t & 15;
    const int rq = t >> 4;
    const int i0 = blockIdx.x * 32;

    const int kl = t & 31, r0 = t >> 5;
    const int fw = t & 63, kq = t >> 6;

    float acc[2][4] = {};

    for (int kt = 0; kt < KF; kt += 32) {
        #pragma unroll
        for (int m = 0; m < 4; ++m)
            xs[kl][r0 + 8 * m] = x[(size_t)(i0 + r0 + 8 * m) * KF + kt + kl];
        #pragma unroll
        for (int m = 0; m < 8; ++m)
            Ws[kq + 4 * m][fw] = W[(size_t)(kt + kq + 4 * m) * FF + fw];
        __syncthreads();
        #pragma unroll
        for (int kk = 0; kk < 32; ++kk) {
            float x0 = xs[kk][rq * 2];
            float x1 = xs[kk][rq * 2 + 1];
            f32x4 wv = *(const f32x4*)&Ws[kk][fq * 4];
            #pragma unroll
            for (int v = 0; v < 4; ++v) {
                acc[0][v] += x0 * wv[v];
                acc[1][v] += x1 * wv[v];
            }
        }
        __syncthreads();
    }

    #pragma unroll
    for (int v = 0; v < 4; ++v) {
        int f = fq * 4 + v;
        union { ushort2 q; __hip_bfloat16 h[2]; } pk;
        pk.h[0] = __float2bfloat16(acc[0][v]);
        pk.h[1] = __float2bfloat16(acc[1][v]);
        *(ushort2*)&ht[(size_t)f * NN + i0 + rq * 2] = pk.q;
    }

    f32x4 a1v = *(const f32x4*)&av[fq * 4];
    f32x4 a2v = *(const f32x4*)&av[64 + fq * 4];
    #pragma unroll
    for (int u = 0; u < 2; ++u) {
        float s1 = 0.f, s2 = 0.f;
        #pragma unroll
        for (int v = 0; v < 4; ++v) {
            s1 += acc[u][v] * a1v[v];
            s2 += acc[u][v] * a2v[v];
        }
        ep[0][rq * 2 + u][fq] = s1;
        ep[1][rq * 2 + u][fq] = s2;
    }
    __syncthreads();
    if (t < 32) {
        float s1 = 0.f, s2 = 0.f;
        #pragma unroll
        for (int q = 0; q < 16; ++q) { s1 += ep[0][t][q]; s2 += ep[1][t][q]; }
        e1[i0 + t] = s1 * LOG2E;
        e2[i0 + t] = s2 * LOG2E;
    }
}

// ---------------------------------------------------------------------------
// Kernel B: mask-driven, barrier-free. Wave owns 16 rows x 1024 j.
// adj bits come from the 8 MB transposed mask (L2-resident): one ushort per
// 2 steps per lane, contiguous over steps. P built directly in MFMA A-frag
// regs; 4 MFMAs/step for features + 1 vs all-ones B for the denominator.
// Rolled outer loop (16 iters) x unroll-2 inner: bounded register pressure,
// no mass hoisting, compiler handles fine-grained vmcnt.
// ---------------------------------------------------------------------------
__global__ __launch_bounds__(256, 4) void gat_attn(
    const unsigned short* __restrict__ maskh, const __hip_bfloat16* __restrict__ ht,
    const float* __restrict__ e1, const float* __restrict__ e2,
    float* __restrict__ accs, float* __restrict__ lsums)
{
    const int t     = threadIdx.x;
    const int lane  = t & 63;
    const int wv    = t >> 6;
    const int n16   = lane & 15;
    const int quad  = lane >> 4;
    const int split = blockIdx.x & (JSPLIT - 1);
    const int i0    = (blockIdx.x >> 3) * 64 + wv * 16;
    const int j0    = split * JW;
    const int row   = i0 + n16;

    const float e1L = e1[row];
    float ms = e1L + MSHIFT * LOG2E;
    const float miL = ms > 0.f ? ms : GAT_ALPHA * ms;
    const float c0  = e1L - miL;                 // t0 = e2 + c0
    const float c1  = GAT_ALPHA * e1L - miL;     // t1 = fma(alpha, e2, c1)

    // ushort index: (row*1024 + split*128 + quad*32)/2 + c
    const unsigned short* mp = maskh + (size_t)row * 512 + split * 64 + quad * 16;
    const float*          epx = e2 + j0 + quad * 8;
    const __hip_bfloat16* hp  = ht + (size_t)n16 * NN + j0 + quad * 8;

    f32x4 dacc[4] = {{0.f,0.f,0.f,0.f},{0.f,0.f,0.f,0.f},{0.f,0.f,0.f,0.f},{0.f,0.f,0.f,0.f}};
    f32x4 dl = {0.f, 0.f, 0.f, 0.f};

    union { unsigned short s[8]; bf16x8 v; } ones;
    #pragma unroll
    for (int k = 0; k < 8; ++k) ones.s[k] = 0x3F80;   // bf16 1.0

    unsigned mh = mp[0];
    for (int c = 0; c < KSTEPS / 2; ++c) {        // rolled: 16 iterations
        const unsigned mcur = mh;
        if (c + 1 < KSTEPS / 2) mh = mp[c + 1];   // tiny L1-hot prefetch

        #pragma unroll
        for (int k = 0; k < 2; ++k) {
            const int st = c * 2 + k;
            float4 e0 = *(const float4*)(epx + st * 32);
            float4 ev = *(const float4*)(epx + st * 32 + 4);
            bf16x8 b0 = *(const bf16x8*)(hp + (size_t)st * 32);
            bf16x8 b1 = *(const bf16x8*)(hp + (size_t)16 * NN + st * 32);
            bf16x8 b2 = *(const bf16x8*)(hp + (size_t)32 * NN + st * 32);
            bf16x8 b3 = *(const bf16x8*)(hp + (size_t)48 * NN + st * 32);

            union { bf16x8 v; __hip_bfloat16 h[8]; } af;
#define PJ(idx, eval)                                                          \
            {                                                                  \
                float t0 = c0 + (eval);                                        \
                float t1 = __builtin_fmaf(GAT_ALPHA, (eval), c1);              \
                float p_ = EXP2F(fmaxf(t0, t1));                               \
                af.h[idx] = __float2bfloat16(                                  \
                    ((mcur >> (k * 8 + idx)) & 1u) ? p_ : 0.f);                \
            }
            PJ(0, e0.x) PJ(1, e0.y) PJ(2, e0.z) PJ(3, e0.w)
            PJ(4, ev.x) PJ(5, ev.y) PJ(6, ev.z) PJ(7, ev.w)
#undef PJ

            dacc[0] = __builtin_amdgcn_mfma_f32_16x16x32_bf16(af.v, b0, dacc[0], 0, 0, 0);
            dacc[1] = __builtin_amdgcn_mfma_f32_16x16x32_bf16(af.v, b1, dacc[1], 0, 0, 0);
            dacc[2] = __builtin_amdgcn_mfma_f32_16x16x32_bf16(af.v, b2, dacc[2], 0, 0, 0);
            dacc[3] = __builtin_amdgcn_mfma_f32_16x16x32_bf16(af.v, b3, dacc[3], 0, 0, 0);
            dl      = __builtin_amdgcn_mfma_f32_16x16x32_bf16(af.v, ones.v, dl, 0, 0, 0);
        }
    }

    // dl D-tile: every column holds the row-sum; lanes n16==0 cover all 16 rows
    if (n16 == 0) {
        #pragma unroll
        for (int r = 0; r < 4; ++r)
            lsums[(size_t)split * NN + i0 + quad * 4 + r] = dl[r];
    }

    // D layout: col = lane&15 (feature), row = quad*4 + reg (m89-verified)
    float* ab = accs + (size_t)split * NN * FF;
    #pragma unroll
    for (int ft = 0; ft < 4; ++ft)
        #pragma unroll
        for (int r = 0; r < 4; ++r)
            ab[(size_t)(i0 + quad * 4 + r) * FF + ft * 16 + n16] = dacc[ft][r];
}

// ---------------------------------------------------------------------------
// Epilogue: out = elu( (sum_s accs[s]) / (sum_s lsums[s]) )
// ---------------------------------------------------------------------------
__global__ __launch_bounds__(256) void gat_epilogue(
    const float* __restrict__ accs, const float* __restrict__ lsums,
    float* __restrict__ out)
{
    const int idx = (blockIdx.x * 256 + threadIdx.x) * 4;  // 4 consecutive f, same row
    const int row = idx >> 6;

    float l = 0.f;
    #pragma unroll
    for (int s = 0; s < JSPLIT; ++s) l += lsums[(size_t)s * NN + row];

    f32x4 a = {0.f, 0.f, 0.f, 0.f};
    #pragma unroll
    for (int s = 0; s < JSPLIT; ++s) {
        f32x4 v = *(const f32x4*)(accs + (size_t)s * NN * FF + idx);
        a.x += v.x; a.y += v.y; a.z += v.z; a.w += v.w;
    }

    const float li = 1.f / l;
    f32x4 o;
    #pragma unroll
    for (int v = 0; v < 4; ++v) {
        float hv = a[v] * li;
        o[v] = hv > 0.f ? hv : __expf(hv) - 1.f;
    }
    *(f32x4*)(out + idx) = o;
}

extern "C" void kernel_launch(void* const* d_in, const int* in_sizes, int n_in,
                              void* d_out, int out_size, void* d_ws, size_t ws_size,
                              hipStream_t stream) {
    const float* x   = (const float*)d_in[0];
    const int*   adj = (const int*)d_in[1];
    const float* W   = (const float*)d_in[2];
    const float* av  = (const float*)d_in[3];
    float* out = (float*)d_out;

    // ws: ht bf16[64*8192] (1MB) | e1 f32[8192] | e2 f32[8192]
    //     | mask 8MB | accs f32[8][8192*64] (16MB) | lsums f32[8][8192] (256KB)
    char* wsb = (char*)d_ws;
    __hip_bfloat16* ht = (__hip_bfloat16*)wsb;
    float* e1    = (float*)(wsb + (1 << 20));
    float* e2    = e1 + NN;
    unsigned* mask = (unsigned*)(e2 + NN);
    float* accs  = (float*)((char*)mask + (size_t)NN * 1024);
    float* lsums = accs + (size_t)JSPLIT * NN * FF;

    adj_compress<<<NN * 256 / 256, 256, 0, stream>>>(adj, mask);  // 2M dwords
    gat_linear<<<256, 256, 0, stream>>>(x, W, av, ht, e1, e2);
    gat_attn<<<(NN / 64) * JSPLIT, 256, 0, stream>>>(
        (const unsigned short*)mask, ht, e1, e2, accs, lsums);
    gat_epilogue<<<NN * FF / 1024, 256, 0, stream>>>(accs, lsums, out);
}

// Round 9
// 470.628 us; speedup vs baseline: 1.0073x; 1.0073x over previous
//
#include <hip/hip_runtime.h>
#include <hip/hip_bf16.h>

#define NN 8192
#define KF 512
#define FF 64
#define GAT_ALPHA 0.2f
#define MSHIFT 20.0f          // safe upper bound on max_j e2[j] (pre-scale)
#define LOG2E 1.44269504f

#define JSPLIT 8              // grid = 128 row-groups x 8 = 1024 blocks = 4/CU
#define JW (NN / JSPLIT)      // 1024 j per wave
#define KSTEPS (JW / 32)      // 32 k-steps of 32

#define EXP2F(x) __builtin_amdgcn_exp2f(x)

typedef __attribute__((ext_vector_type(8))) __bf16 bf16x8;
typedef __attribute__((ext_vector_type(4))) float f32x4;
typedef __attribute__((ext_vector_type(4))) int   i32x4;

// RNE fp32->bf16 pair pack, pure bit ops (SROA-safe, no unions/structs).
// Returns (bf16(hi) << 16) | bf16(lo).
__device__ __forceinline__ unsigned pack_bf16_rne(float hi, float lo) {
    unsigned uh = __float_as_uint(hi);
    unsigned ul = __float_as_uint(lo);
    uh = uh + 0x7FFFu + ((uh >> 16) & 1u);
    ul = ul + 0x7FFFu + ((ul >> 16) & 1u);
    return (uh & 0xFFFF0000u) | (ul >> 16);
}

// ---------------------------------------------------------------------------
// adj_compress: 268 MB int32 adjacency -> 8 MB bitmask, transposed to the
// MFMA A-fragment lane order: byte addr = row*1024 + split*128 + quad*32 + st,
// bit jj of that byte = adj[row][split*1024 + st*32 + quad*8 + jj] > 0.
// ---------------------------------------------------------------------------
__global__ __launch_bounds__(256) void adj_compress(
    const int* __restrict__ adj, unsigned* __restrict__ mask)
{
    const int b   = blockIdx.x * 256 + threadIdx.x;  // dword index, 2M total
    const int st4 =  b       & 7;
    const int q   = (b >> 3) & 3;
    const int s   = (b >> 5) & 7;
    const int row =  b >> 8;

    const int* ap = adj + (size_t)row * NN + s * JW + q * 8;
    unsigned w = 0;
    #pragma unroll
    for (int k = 0; k < 4; ++k) {
        const int st = st4 * 4 + k;
        int4 a0 = *(const int4*)(ap + st * 32);
        int4 a1 = *(const int4*)(ap + st * 32 + 4);
        unsigned by =  (unsigned)(a0.x > 0)
                    | ((unsigned)(a0.y > 0) << 1)
                    | ((unsigned)(a0.z > 0) << 2)
                    | ((unsigned)(a0.w > 0) << 3)
                    | ((unsigned)(a1.x > 0) << 4)
                    | ((unsigned)(a1.y > 0) << 5)
                    | ((unsigned)(a1.z > 0) << 6)
                    | ((unsigned)(a1.w > 0) << 7);
        w |= by << (8 * k);
    }
    mask[b] = w;
}

// ---------------------------------------------------------------------------
// Kernel A: h = x@W (fp32), e1/e2 = (h@a1, h@a2) * log2(e),
//           ht = h^T bf16 [64][8192]. 256 blocks x 256 thr, 32 rows/block.
// ---------------------------------------------------------------------------
__global__ __launch_bounds__(256) void gat_linear(
    const float* __restrict__ x, const float* __restrict__ W,
    const float* __restrict__ av, __hip_bfloat16* __restrict__ ht,
    float* __restrict__ e1, float* __restrict__ e2)
{
    __shared__ float xs[32][33];
    __shared__ float Ws[32][64];
    __shared__ float ep[2][32][17];

    const int t  = threadIdx.x;
    const int fq = t & 15;
    const int rq = t >> 4;
    const int i0 = blockIdx.x * 32;

    const int kl = t & 31, r0 = t >> 5;
    const int fw = t & 63, kq = t >> 6;

    float acc[2][4] = {};

    for (int kt = 0; kt < KF; kt += 32) {
        #pragma unroll
        for (int m = 0; m < 4; ++m)
            xs[kl][r0 + 8 * m] = x[(size_t)(i0 + r0 + 8 * m) * KF + kt + kl];
        #pragma unroll
        for (int m = 0; m < 8; ++m)
            Ws[kq + 4 * m][fw] = W[(size_t)(kt + kq + 4 * m) * FF + fw];
        __syncthreads();
        #pragma unroll
        for (int kk = 0; kk < 32; ++kk) {
            float x0 = xs[kk][rq * 2];
            float x1 = xs[kk][rq * 2 + 1];
            f32x4 wv = *(const f32x4*)&Ws[kk][fq * 4];
            #pragma unroll
            for (int v = 0; v < 4; ++v) {
                acc[0][v] += x0 * wv[v];
                acc[1][v] += x1 * wv[v];
            }
        }
        __syncthreads();
    }

    // ht store: two bf16 rows packed in one dword (no unions)
    #pragma unroll
    for (int v = 0; v < 4; ++v) {
        int f = fq * 4 + v;
        unsigned w = pack_bf16_rne(acc[1][v], acc[0][v]);
        *(unsigned*)&ht[(size_t)f * NN + i0 + rq * 2] = w;
    }

    f32x4 a1v = *(const f32x4*)&av[fq * 4];
    f32x4 a2v = *(const f32x4*)&av[64 + fq * 4];
    #pragma unroll
    for (int u = 0; u < 2; ++u) {
        float s1 = 0.f, s2 = 0.f;
        #pragma unroll
        for (int v = 0; v < 4; ++v) {
            s1 += acc[u][v] * a1v[v];
            s2 += acc[u][v] * a2v[v];
        }
        ep[0][rq * 2 + u][fq] = s1;
        ep[1][rq * 2 + u][fq] = s2;
    }
    __syncthreads();
    if (t < 32) {
        float s1 = 0.f, s2 = 0.f;
        #pragma unroll
        for (int q = 0; q < 16; ++q) { s1 += ep[0][t][q]; s2 += ep[1][t][q]; }
        e1[i0 + t] = s1 * LOG2E;
        e2[i0 + t] = s2 * LOG2E;
    }
}

// ---------------------------------------------------------------------------
// Kernel B: mask-driven, barrier-free, SROA-safe (no unions, no indexed
// arrays -> nothing can be demoted to scratch). Wave owns 16 rows x 1024 j.
// A-frag built as named scalars -> RNE bit-pack -> i32x4 -> bit_cast bf16x8.
// 4 MFMAs/step for features + 1 vs all-ones B for the denominator.
// ---------------------------------------------------------------------------
__global__ __launch_bounds__(256, 4) void gat_attn(
    const unsigned short* __restrict__ maskh, const __hip_bfloat16* __restrict__ ht,
    const float* __restrict__ e1, const float* __restrict__ e2,
    float* __restrict__ accs, float* __restrict__ lsums)
{
    const int t     = threadIdx.x;
    const int lane  = t & 63;
    const int wv    = t >> 6;
    const int n16   = lane & 15;
    const int quad  = lane >> 4;
    const int split = blockIdx.x & (JSPLIT - 1);
    const int i0    = (blockIdx.x >> 3) * 64 + wv * 16;
    const int j0    = split * JW;
    const int row   = i0 + n16;

    const float e1L = e1[row];
    float ms = e1L + MSHIFT * LOG2E;
    const float miL = ms > 0.f ? ms : GAT_ALPHA * ms;
    const float c0  = e1L - miL;                 // t0 = e2 + c0
    const float c1  = GAT_ALPHA * e1L - miL;     // t1 = fma(alpha, e2, c1)

    const unsigned short* mp  = maskh + (size_t)row * 512 + split * 64 + quad * 16;
    const float*          epx = e2 + j0 + quad * 8;
    const __hip_bfloat16* hp  = ht + (size_t)n16 * NN + j0 + quad * 8;

    f32x4 dacc0 = {0.f,0.f,0.f,0.f}, dacc1 = {0.f,0.f,0.f,0.f};
    f32x4 dacc2 = {0.f,0.f,0.f,0.f}, dacc3 = {0.f,0.f,0.f,0.f};
    f32x4 dl    = {0.f,0.f,0.f,0.f};

    const i32x4 ones_i = {0x3F803F80, 0x3F803F80, 0x3F803F80, 0x3F803F80};
    const bf16x8 ones  = __builtin_bit_cast(bf16x8, ones_i);

    unsigned mh = mp[0];
    for (int c = 0; c < KSTEPS / 2; ++c) {        // rolled: 16 iterations
        const unsigned mcur = mh;
        if (c + 1 < KSTEPS / 2) mh = mp[c + 1];

        #pragma unroll
        for (int k = 0; k < 2; ++k) {
            const int st = c * 2 + k;
            f32x4 e0 = *(const f32x4*)(epx + st * 32);
            f32x4 ev = *(const f32x4*)(epx + st * 32 + 4);
            bf16x8 b0 = *(const bf16x8*)(hp + (size_t)st * 32);
            bf16x8 b1 = *(const bf16x8*)(hp + (size_t)16 * NN + st * 32);
            bf16x8 b2 = *(const bf16x8*)(hp + (size_t)32 * NN + st * 32);
            bf16x8 b3 = *(const bf16x8*)(hp + (size_t)48 * NN + st * 32);

#define PJ(eval, bit)                                                          \
            ( ((mcur >> (bit)) & 1u)                                           \
                ? EXP2F(fmaxf(c0 + (eval), __builtin_fmaf(GAT_ALPHA, (eval), c1))) \
                : 0.f )
            float p0 = PJ(e0.x, k * 8 + 0);
            float p1 = PJ(e0.y, k * 8 + 1);
            float p2 = PJ(e0.z, k * 8 + 2);
            float p3 = PJ(e0.w, k * 8 + 3);
            float p4 = PJ(ev.x, k * 8 + 4);
            float p5 = PJ(ev.y, k * 8 + 5);
            float p6 = PJ(ev.z, k * 8 + 6);
            float p7 = PJ(ev.w, k * 8 + 7);
#undef PJ
            i32x4 iv;
            iv.x = (int)pack_bf16_rne(p1, p0);
            iv.y = (int)pack_bf16_rne(p3, p2);
            iv.z = (int)pack_bf16_rne(p5, p4);
            iv.w = (int)pack_bf16_rne(p7, p6);
            bf16x8 af = __builtin_bit_cast(bf16x8, iv);

            dacc0 = __builtin_amdgcn_mfma_f32_16x16x32_bf16(af, b0, dacc0, 0, 0, 0);
            dacc1 = __builtin_amdgcn_mfma_f32_16x16x32_bf16(af, b1, dacc1, 0, 0, 0);
            dacc2 = __builtin_amdgcn_mfma_f32_16x16x32_bf16(af, b2, dacc2, 0, 0, 0);
            dacc3 = __builtin_amdgcn_mfma_f32_16x16x32_bf16(af, b3, dacc3, 0, 0, 0);
            dl    = __builtin_amdgcn_mfma_f32_16x16x32_bf16(af, ones, dl, 0, 0, 0);
        }
    }

    // dl D-tile: every column holds the row-sum; lanes n16==0 cover all 16 rows
    if (n16 == 0) {
        lsums[(size_t)split * NN + i0 + quad * 4 + 0] = dl.x;
        lsums[(size_t)split * NN + i0 + quad * 4 + 1] = dl.y;
        lsums[(size_t)split * NN + i0 + quad * 4 + 2] = dl.z;
        lsums[(size_t)split * NN + i0 + quad * 4 + 3] = dl.w;
    }

    // D layout: col = lane&15 (feature), row = quad*4 + reg (m89-verified)
    float* ab = accs + (size_t)split * NN * FF + (size_t)(i0 + quad * 4) * FF + n16;
#define STORE4(dv, ftofs)                                                      \
    ab[0 * FF + (ftofs)] = (dv).x;                                             \
    ab[1 * FF + (ftofs)] = (dv).y;                                             \
    ab[2 * FF + (ftofs)] = (dv).z;                                             \
    ab[3 * FF + (ftofs)] = (dv).w;
    STORE4(dacc0, 0)
    STORE4(dacc1, 16)
    STORE4(dacc2, 32)
    STORE4(dacc3, 48)
#undef STORE4
}

// ---------------------------------------------------------------------------
// Epilogue: out = elu( (sum_s accs[s]) / (sum_s lsums[s]) )
// ---------------------------------------------------------------------------
__global__ __launch_bounds__(256) void gat_epilogue(
    const float* __restrict__ accs, const float* __restrict__ lsums,
    float* __restrict__ out)
{
    const int idx = (blockIdx.x * 256 + threadIdx.x) * 4;  // 4 consecutive f, same row
    const int row = idx >> 6;

    float l = 0.f;
    #pragma unroll
    for (int s = 0; s < JSPLIT; ++s) l += lsums[(size_t)s * NN + row];

    f32x4 a = {0.f, 0.f, 0.f, 0.f};
    #pragma unroll
    for (int s = 0; s < JSPLIT; ++s) {
        f32x4 v = *(const f32x4*)(accs + (size_t)s * NN * FF + idx);
        a.x += v.x; a.y += v.y; a.z += v.z; a.w += v.w;
    }

    const float li = 1.f / l;
    f32x4 o;
    o.x = a.x * li; o.y = a.y * li; o.z = a.z * li; o.w = a.w * li;
    o.x = o.x > 0.f ? o.x : __expf(o.x) - 1.f;
    o.y = o.y > 0.f ? o.y : __expf(o.y) - 1.f;
    o.z = o.z > 0.f ? o.z : __expf(o.z) - 1.f;
    o.w = o.w > 0.f ? o.w : __expf(o.w) - 1.f;
    *(f32x4*)(out + idx) = o;
}

extern "C" void kernel_launch(void* const* d_in, const int* in_sizes, int n_in,
                              void* d_out, int out_size, void* d_ws, size_t ws_size,
                              hipStream_t stream) {
    const float* x   = (const float*)d_in[0];
    const int*   adj = (const int*)d_in[1];
    const float* W   = (const float*)d_in[2];
    const float* av  = (const float*)d_in[3];
    float* out = (float*)d_out;

    // ws: ht bf16[64*8192] (1MB) | e1 f32[8192] | e2 f32[8192]
    //     | mask 8MB | accs f32[8][8192*64] (16MB) | lsums f32[8][8192] (256KB)
    char* wsb = (char*)d_ws;
    __hip_bfloat16* ht = (__hip_bfloat16*)wsb;
    float* e1    = (float*)(wsb + (1 << 20));
    float* e2    = e1 + NN;
    unsigned* mask = (unsigned*)(e2 + NN);
    float* accs  = (float*)((char*)mask + (size_t)NN * 1024);
    float* lsums = accs + (size_t)JSPLIT * NN * FF;

    adj_compress<<<NN * 256 / 256, 256, 0, stream>>>(adj, mask);
    gat_linear<<<256, 256, 0, stream>>>(x, W, av, ht, e1, e2);
    gat_attn<<<(NN / 64) * JSPLIT, 256, 0, stream>>>(
        (const unsigned short*)mask, ht, e1, e2, accs, lsums);
    gat_epilogue<<<NN * FF / 1024, 256, 0, stream>>>(accs, lsums, out);
}

// Round 10
// 399.809 us; speedup vs baseline: 1.1857x; 1.1771x over previous
//
#include <hip/hip_runtime.h>
#include <hip/hip_bf16.h>

#define NN 8192
#define KF 512
#define FF 64
#define GAT_ALPHA 0.2f
#define MSHIFT 20.0f          // safe upper bound on max_j e2[j] (pre-scale)
#define LOG2E 1.44269504f

#define JSPLIT 16             // grid = 128 row-groups x 16 = 2048 blocks
#define JW (NN / JSPLIT)      // 512 j per block
#define KSTEPS (JW / 32)      // 16 k-steps of 32

#define HTS 520               // hs row stride (bf16): 260 dwords, %32=4 -> 2-way (free)

#define EXP2F(x) __builtin_amdgcn_exp2f(x)

typedef __attribute__((ext_vector_type(8))) __bf16 bf16x8;
typedef __attribute__((ext_vector_type(4))) float f32x4;

// RNE fp32->bf16 pair pack, pure bit ops. Returns (bf16(hi)<<16)|bf16(lo).
__device__ __forceinline__ unsigned pack_bf16_rne(float hi, float lo) {
    unsigned uh = __float_as_uint(hi);
    unsigned ul = __float_as_uint(lo);
    uh = uh + 0x7FFFu + ((uh >> 16) & 1u);
    ul = ul + 0x7FFFu + ((ul >> 16) & 1u);
    return (uh & 0xFFFF0000u) | (ul >> 16);
}

// ---------------------------------------------------------------------------
// Kernel A: h = x@W (fp32), e1/e2 = (h@a1, h@a2) * log2(e),
//           ht = h^T bf16 [64][8192]. 256 blocks x 256 thr, 32 rows/block.
// ---------------------------------------------------------------------------
__global__ __launch_bounds__(256) void gat_linear(
    const float* __restrict__ x, const float* __restrict__ W,
    const float* __restrict__ av, __hip_bfloat16* __restrict__ ht,
    float* __restrict__ e1, float* __restrict__ e2)
{
    __shared__ float xs[32][33];
    __shared__ float Ws[32][64];
    __shared__ float ep[2][32][17];

    const int t  = threadIdx.x;
    const int fq = t & 15;
    const int rq = t >> 4;
    const int i0 = blockIdx.x * 32;

    const int kl = t & 31, r0 = t >> 5;
    const int fw = t & 63, kq = t >> 6;

    float acc[2][4] = {};

    for (int kt = 0; kt < KF; kt += 32) {
        #pragma unroll
        for (int m = 0; m < 4; ++m)
            xs[kl][r0 + 8 * m] = x[(size_t)(i0 + r0 + 8 * m) * KF + kt + kl];
        #pragma unroll
        for (int m = 0; m < 8; ++m)
            Ws[kq + 4 * m][fw] = W[(size_t)(kt + kq + 4 * m) * FF + fw];
        __syncthreads();
        #pragma unroll
        for (int kk = 0; kk < 32; ++kk) {
            float x0 = xs[kk][rq * 2];
            float x1 = xs[kk][rq * 2 + 1];
            f32x4 wv = *(const f32x4*)&Ws[kk][fq * 4];
            #pragma unroll
            for (int v = 0; v < 4; ++v) {
                acc[0][v] += x0 * wv[v];
                acc[1][v] += x1 * wv[v];
            }
        }
        __syncthreads();
    }

    #pragma unroll
    for (int v = 0; v < 4; ++v) {
        int f = fq * 4 + v;
        unsigned w = pack_bf16_rne(acc[1][v], acc[0][v]);
        *(unsigned*)&ht[(size_t)f * NN + i0 + rq * 2] = w;
    }

    f32x4 a1v = *(const f32x4*)&av[fq * 4];
    f32x4 a2v = *(const f32x4*)&av[64 + fq * 4];
    #pragma unroll
    for (int u = 0; u < 2; ++u) {
        float s1 = 0.f, s2 = 0.f;
        #pragma unroll
        for (int v = 0; v < 4; ++v) {
            s1 += acc[u][v] * a1v[v];
            s2 += acc[u][v] * a2v[v];
        }
        ep[0][rq * 2 + u][fq] = s1;
        ep[1][rq * 2 + u][fq] = s2;
    }
    __syncthreads();
    if (t < 32) {
        float s1 = 0.f, s2 = 0.f;
        #pragma unroll
        for (int q = 0; q < 16; ++q) { s1 += ep[0][t][q]; s2 += ep[1][t][q]; }
        e1[i0 + t] = s1 * LOG2E;
        e2[i0 + t] = s2 * LOG2E;
    }
}

// ---------------------------------------------------------------------------
// Kernel B: LDS-resident hot loop. Block = 64 rows x 512 j.
// Prologue (streaming, once): ht slice 64KB -> LDS hs[64][520];
// e2 slice 2KB -> LDS; adj slice 128KB (coalesced, read once grid-wide)
// -> 4.3KB LDS bitmask msk[st][quad][row]. One barrier.
// Loop: 16 steps, ONLY ds_read + VALU + MFMA, 1-step register prefetch.
// A-frag = P (A[m=lane&15][k=quad*8+jj]); 4 feature-MFMAs + 1 ones-MFMA (=l).
// ---------------------------------------------------------------------------
__global__ __launch_bounds__(256) void gat_attn(
    const int* __restrict__ adj, const __hip_bfloat16* __restrict__ ht,
    const float* __restrict__ e1, const float* __restrict__ e2,
    float* __restrict__ accs, float* __restrict__ lsums)
{
    __shared__ __hip_bfloat16 hs[64 * HTS];            // 66560 B
    __shared__ float e2s[JW];                          // 2048 B
    __shared__ unsigned char msk[KSTEPS * 4 * 68];     // 4352 B  [st][quad][row(+pad)]

    const int t     = threadIdx.x;
    const int lane  = t & 63;
    const int wv    = t >> 6;
    const int n16   = lane & 15;
    const int quad  = lane >> 4;
    const int split = blockIdx.x & (JSPLIT - 1);
    const int i0b   = (blockIdx.x >> 4) * 64;          // block row base
    const int i0    = i0b + wv * 16;                   // wave row base
    const int j0    = split * JW;
    const int rowl  = wv * 16 + n16;                   // wave-local row 0..63? no: block-local
    const int row   = i0 + n16;                        // global row

    // ---- stage ht slice: [64][512] bf16, coalesced ----
    #pragma unroll
    for (int k = 0; k < 16; ++k) {
        int g  = t + k * 256;          // 4096 chunks of 8 bf16
        int f  = g >> 6;
        int jl = (g & 63) * 8;
        *(bf16x8*)&hs[f * HTS + jl] =
            *(const bf16x8*)&ht[(size_t)f * NN + j0 + jl];
    }
    // ---- stage e2 slice ----
    if (t < JW / 4)
        *(float4*)&e2s[t * 4] = *(const float4*)&e2[j0 + t * 4];

    // ---- adj slice -> LDS bitmask (adj read once grid-wide) ----
    {
        const int st = t & 15;
        #pragma unroll
        for (int rep = 0; rep < 4; ++rep) {
            const int r = rep * 16 + (t >> 4);         // block-local row 0..63
            const int* ap = adj + (size_t)(i0b + r) * NN + j0 + st * 32;
            unsigned w = 0;
            #pragma unroll
            for (int k = 0; k < 8; ++k) {
                int4 v = *(const int4*)(ap + k * 4);
                unsigned nib =  (unsigned)(v.x > 0)
                             | ((unsigned)(v.y > 0) << 1)
                             | ((unsigned)(v.z > 0) << 2)
                             | ((unsigned)(v.w > 0) << 3);
                w |= nib << (k * 4);
            }
            msk[(st * 4 + 0) * 68 + r] = (unsigned char)(w       & 0xFF);
            msk[(st * 4 + 1) * 68 + r] = (unsigned char)((w >> 8)  & 0xFF);
            msk[(st * 4 + 2) * 68 + r] = (unsigned char)((w >> 16) & 0xFF);
            msk[(st * 4 + 3) * 68 + r] = (unsigned char)((w >> 24) & 0xFF);
        }
    }
    __syncthreads();

    const float e1L = e1[row];
    float ms = e1L + MSHIFT * LOG2E;
    const float miL = ms > 0.f ? ms : GAT_ALPHA * ms;
    const float c0  = e1L - miL;                 // t0 = e2 + c0
    const float c1  = GAT_ALPHA * e1L - miL;     // t1 = fma(alpha, e2, c1)

    const __hip_bfloat16* hp = hs + rowl * 0 + n16 * HTS + quad * 8;  // B rows n16,+16,+32,+48
    const float* ep0 = e2s + quad * 8;

    f32x4 dacc0 = {0.f,0.f,0.f,0.f}, dacc1 = {0.f,0.f,0.f,0.f};
    f32x4 dacc2 = {0.f,0.f,0.f,0.f}, dacc3 = {0.f,0.f,0.f,0.f};
    f32x4 dl    = {0.f,0.f,0.f,0.f};

    typedef __attribute__((ext_vector_type(4))) int i32x4;
    const i32x4 ones_i = {0x3F803F80, 0x3F803F80, 0x3F803F80, 0x3F803F80};
    const bf16x8 ones  = __builtin_bit_cast(bf16x8, ones_i);

    // prefetch step 0
    unsigned mb = msk[(0 * 4 + quad) * 68 + rowl];
    f32x4  e0 = *(const f32x4*)(ep0);
    f32x4  ev = *(const f32x4*)(ep0 + 4);
    bf16x8 b0 = *(const bf16x8*)(hp);
    bf16x8 b1 = *(const bf16x8*)(hp + 16 * HTS);
    bf16x8 b2 = *(const bf16x8*)(hp + 32 * HTS);
    bf16x8 b3 = *(const bf16x8*)(hp + 48 * HTS);

    for (int st = 0; st < KSTEPS; ++st) {
        const unsigned mc = mb;
        const f32x4  ce0 = e0, cev = ev;
        const bf16x8 cb0 = b0, cb1 = b1, cb2 = b2, cb3 = b3;
        if (st + 1 < KSTEPS) {
            mb = msk[((st + 1) * 4 + quad) * 68 + rowl];
            e0 = *(const f32x4*)(ep0 + (st + 1) * 32);
            ev = *(const f32x4*)(ep0 + (st + 1) * 32 + 4);
            b0 = *(const bf16x8*)(hp + (st + 1) * 32);
            b1 = *(const bf16x8*)(hp + 16 * HTS + (st + 1) * 32);
            b2 = *(const bf16x8*)(hp + 32 * HTS + (st + 1) * 32);
            b3 = *(const bf16x8*)(hp + 48 * HTS + (st + 1) * 32);
        }

#define PJ(eval, bit)                                                          \
        ( ((mc >> (bit)) & 1u)                                                 \
            ? EXP2F(fmaxf(c0 + (eval), __builtin_fmaf(GAT_ALPHA, (eval), c1))) \
            : 0.f )
        float p0 = PJ(ce0.x, 0);
        float p1 = PJ(ce0.y, 1);
        float p2 = PJ(ce0.z, 2);
        float p3 = PJ(ce0.w, 3);
        float p4 = PJ(cev.x, 4);
        float p5 = PJ(cev.y, 5);
        float p6 = PJ(cev.z, 6);
        float p7 = PJ(cev.w, 7);
#undef PJ
        i32x4 iv;
        iv.x = (int)pack_bf16_rne(p1, p0);
        iv.y = (int)pack_bf16_rne(p3, p2);
        iv.z = (int)pack_bf16_rne(p5, p4);
        iv.w = (int)pack_bf16_rne(p7, p6);
        bf16x8 af = __builtin_bit_cast(bf16x8, iv);

        dacc0 = __builtin_amdgcn_mfma_f32_16x16x32_bf16(af, cb0, dacc0, 0, 0, 0);
        dacc1 = __builtin_amdgcn_mfma_f32_16x16x32_bf16(af, cb1, dacc1, 0, 0, 0);
        dacc2 = __builtin_amdgcn_mfma_f32_16x16x32_bf16(af, cb2, dacc2, 0, 0, 0);
        dacc3 = __builtin_amdgcn_mfma_f32_16x16x32_bf16(af, cb3, dacc3, 0, 0, 0);
        dl    = __builtin_amdgcn_mfma_f32_16x16x32_bf16(af, ones, dl, 0, 0, 0);
    }

    // dl D-tile: every column holds the row-sum; lanes n16==0 cover all 16 rows
    if (n16 == 0) {
        lsums[(size_t)split * NN + i0 + quad * 4 + 0] = dl.x;
        lsums[(size_t)split * NN + i0 + quad * 4 + 1] = dl.y;
        lsums[(size_t)split * NN + i0 + quad * 4 + 2] = dl.z;
        lsums[(size_t)split * NN + i0 + quad * 4 + 3] = dl.w;
    }

    // D layout: col = lane&15 (feature), row = quad*4 + reg (m89-verified)
    float* ab = accs + (size_t)split * NN * FF + (size_t)(i0 + quad * 4) * FF + n16;
#define STORE4(dv, ftofs)                                                      \
    ab[0 * FF + (ftofs)] = (dv).x;                                             \
    ab[1 * FF + (ftofs)] = (dv).y;                                             \
    ab[2 * FF + (ftofs)] = (dv).z;                                             \
    ab[3 * FF + (ftofs)] = (dv).w;
    STORE4(dacc0, 0)
    STORE4(dacc1, 16)
    STORE4(dacc2, 32)
    STORE4(dacc3, 48)
#undef STORE4
}

// ---------------------------------------------------------------------------
// Epilogue: out = elu( (sum_s accs[s]) / (sum_s lsums[s]) )
// ---------------------------------------------------------------------------
__global__ __launch_bounds__(256) void gat_epilogue(
    const float* __restrict__ accs, const float* __restrict__ lsums,
    float* __restrict__ out)
{
    const int idx = (blockIdx.x * 256 + threadIdx.x) * 4;  // 4 consecutive f, same row
    const int row = idx >> 6;

    float l = 0.f;
    #pragma unroll
    for (int s = 0; s < JSPLIT; ++s) l += lsums[(size_t)s * NN + row];

    f32x4 a = {0.f, 0.f, 0.f, 0.f};
    #pragma unroll
    for (int s = 0; s < JSPLIT; ++s) {
        f32x4 v = *(const f32x4*)(accs + (size_t)s * NN * FF + idx);
        a.x += v.x; a.y += v.y; a.z += v.z; a.w += v.w;
    }

    const float li = 1.f / l;
    f32x4 o;
    o.x = a.x * li; o.y = a.y * li; o.z = a.z * li; o.w = a.w * li;
    o.x = o.x > 0.f ? o.x : __expf(o.x) - 1.f;
    o.y = o.y > 0.f ? o.y : __expf(o.y) - 1.f;
    o.z = o.z > 0.f ? o.z : __expf(o.z) - 1.f;
    o.w = o.w > 0.f ? o.w : __expf(o.w) - 1.f;
    *(f32x4*)(out + idx) = o;
}

extern "C" void kernel_launch(void* const* d_in, const int* in_sizes, int n_in,
                              void* d_out, int out_size, void* d_ws, size_t ws_size,
                              hipStream_t stream) {
    const float* x   = (const float*)d_in[0];
    const int*   adj = (const int*)d_in[1];
    const float* W   = (const float*)d_in[2];
    const float* av  = (const float*)d_in[3];
    float* out = (float*)d_out;

    // ws: ht bf16[64*8192] (1MB) | e1 f32[8192] | e2 f32[8192]
    //     | accs f32[16][8192*64] (32MB) | lsums f32[16][8192] (512KB)
    char* wsb = (char*)d_ws;
    __hip_bfloat16* ht = (__hip_bfloat16*)wsb;
    float* e1    = (float*)(wsb + (1 << 20));
    float* e2    = e1 + NN;
    float* accs  = e2 + NN;
    float* lsums = accs + (size_t)JSPLIT * NN * FF;

    gat_linear<<<256, 256, 0, stream>>>(x, W, av, ht, e1, e2);
    gat_attn<<<(NN / 64) * JSPLIT, 256, 0, stream>>>(adj, ht, e1, e2, accs, lsums);
    gat_epilogue<<<NN * FF / 1024, 256, 0, stream>>>(accs, lsums, out);
}